// Round 5
// baseline (70.737 us; speedup 1.0000x reference)
//
#include <hip/hip_runtime.h>
#include <cstdint>

typedef short bf16x8 __attribute__((ext_vector_type(8)));
typedef float f32x4 __attribute__((ext_vector_type(4)));

#define NO 8
#define NT 4
#define ND 256
#define NH1 64
#define NH2 32
#define BM 64
#define BNEPS 1e-5f

__device__ __forceinline__ unsigned bfpack2(float a, float b) {
    unsigned ua = __float_as_uint(a), ub = __float_as_uint(b);
    ua = (ua + 0x7FFFu + ((ua >> 16) & 1u)) >> 16;
    ub = (ub + 0x7FFFu + ((ub >> 16) & 1u)) >> 16;
    return ua | (ub << 16);
}

// ws layout: int[0..3]=cnt, [4..7]=padded base, [8]=padded total, [12..15]=cursor,
// [16..16+B+256)=perm (filled -1; pad slots stay -1), then W1T (1MB), W2T (128KB).

__global__ void k_init(int* __restrict__ ws, int* __restrict__ perm, int n) {
    const int gi = blockIdx.x * blockDim.x + threadIdx.x;
    if (gi < 16) ws[gi] = 0;
    if (gi < n) perm[gi] = -1;
}

__global__ void k_hist(const int* __restrict__ trt, int* __restrict__ cnt, int B) {
    __shared__ int loc[NT];
    const int tid = threadIdx.x;
    if (tid < NT) loc[tid] = 0;
    __syncthreads();
    const int i = blockIdx.x * blockDim.x + tid;
    if (i < B) atomicAdd(&loc[trt[i] & 3], 1);
    __syncthreads();
    if (tid < NT) atomicAdd(&cnt[tid], loc[tid]);
}

__global__ void k_prefix(int* __restrict__ ws) {
    int b = 0;
#pragma unroll
    for (int t = 0; t < NT; ++t) {
        ws[4 + t] = b; ws[12 + t] = b;
        b += (ws[t] + BM - 1) & ~(BM - 1);       // 64-aligned buckets
    }
    ws[8] = b;
}

__global__ void k_scatter(const int* __restrict__ trt, int* __restrict__ ws,
                          int* __restrict__ perm, int B) {
    __shared__ int loc[NT], gb[NT];
    const int tid = threadIdx.x;
    if (tid < NT) loc[tid] = 0;
    __syncthreads();
    const int i = blockIdx.x * blockDim.x + tid;
    int tt = 0, pos = 0;
    if (i < B) { tt = trt[i] & 3; pos = atomicAdd(&loc[tt], 1); }
    __syncthreads();
    if (tid < NT) gb[tid] = atomicAdd(&ws[12 + tid], loc[tid]);
    __syncthreads();
    if (i < B) perm[gb[tt] + pos] = i;
}

// ---------------- fused weight prep: fp32 -> bf16 fragment-linear ----------------
// W1T: frag gi = ((t*8 + c)*32 + nt)*64 + lane; lane = kg*16 + n16;
//      n = nt*16+n16 (o=n>>6,h=n&63), k = c*32 + kg*8 + j
// W2T: [t][o][kt(2)][ks(2)][kg(4)][m16(16)][j(8)]
__global__ __launch_bounds__(256) void k_prep(const float* __restrict__ W1,
                                              const float* __restrict__ W2,
                                              unsigned* __restrict__ W1T4,
                                              unsigned* __restrict__ W2T4) {
    const int bid = blockIdx.x, tid = threadIdx.x;
    if (bid < 256) {
        const int gi = bid * 256 + tid;                   // 65536 frags
        const int lane = gi & 63, nt = (gi >> 6) & 31, c = (gi >> 11) & 7, t = gi >> 14;
        const int n16 = lane & 15, kg = lane >> 4;
        const int n = nt * 16 + n16, o = n >> 6, h = n & 63;
        const int k0 = c * 32 + kg * 8;
        const float* src = W1 + ((size_t)(o * NT + t) * ND + k0) * NH1 + h;
        float v[8];
#pragma unroll
        for (int j = 0; j < 8; ++j) v[j] = src[(size_t)j * NH1];
        uint4 q;
        q.x = bfpack2(v[0], v[1]); q.y = bfpack2(v[2], v[3]);
        q.z = bfpack2(v[4], v[5]); q.w = bfpack2(v[6], v[7]);
        ((uint4*)W1T4)[gi] = q;
    } else {
        const int gi = (bid - 256) * 256 + tid;           // 8192 frags
        const int m16 = gi & 15, kg = (gi >> 4) & 3, ks = (gi >> 6) & 1,
                  kt = (gi >> 7) & 1, o = (gi >> 8) & 7, t = gi >> 11;
        const int k2 = kt * 16 + m16, hb = ks * 32 + kg * 8;
        const float* src = W2 + ((size_t)(o * NT + t) * NH1 + hb) * NH2 + k2;
        float v[8];
#pragma unroll
        for (int j = 0; j < 8; ++j) v[j] = src[(size_t)j * NH2];
        uint4 q;
        q.x = bfpack2(v[0], v[1]); q.y = bfpack2(v[2], v[3]);
        q.z = bfpack2(v[4], v[5]); q.w = bfpack2(v[6], v[7]);
        ((uint4*)W2T4)[gi] = q;
    }
}

// ---------------- fused 3-layer expert MLP: X-upfront, barrier-free K-loop ----------------
__global__ __launch_bounds__(256, 2) void k_main(
    const float* __restrict__ X, const int* __restrict__ ws, const int* __restrict__ perm,
    const unsigned short* __restrict__ W1T, const unsigned short* __restrict__ W2T,
    const float* __restrict__ pb1, const float* __restrict__ pg1, const float* __restrict__ pbe1,
    const float* __restrict__ pm1, const float* __restrict__ pv1,
    const float* __restrict__ pb2, const float* __restrict__ pg2, const float* __restrict__ pbe2,
    const float* __restrict__ pm2, const float* __restrict__ pv2,
    const float* __restrict__ W3, const float* __restrict__ pb3, float* __restrict__ out)
{
    const int m0 = blockIdx.x * BM;
    if (m0 >= ws[8]) return;
    const int t = (m0 >= ws[5]) + (m0 >= ws[6]) + (m0 >= ws[7]);
    const int tid = threadIdx.x;
    const int w = tid >> 6;
    const int l = tid & 63;

    // [0,32768): X tile [64 rows][512 B] bf16, XOR-swizzled (byte ^= (row&7)<<4)
    // after K-loop the whole [0,65536) becomes Hr[64][1024 B] bf16 swizzled
    __shared__ __align__(16) char LDS[65536];

    const int rid_reg = perm[m0 + l];          // every wave holds all 64 row ids

    // ---- stage ALL of X for this block: 16 coalesced 1KB row loads per wave ----
    {
        uint2 xr[16];
#pragma unroll
        for (int j = 0; j < 16; ++j) {
            const int rr = __shfl(rid_reg, w * 16 + j);
            const int rrow = rr < 0 ? 0 : rr;
            const float4 xv = *(const float4*)(X + (size_t)rrow * ND + l * 4);
            xr[j].x = bfpack2(xv.x, xv.y);
            xr[j].y = bfpack2(xv.z, xv.w);
        }
#pragma unroll
        for (int j = 0; j < 16; ++j) {
            const int r = w * 16 + j;
            *(uint2*)(LDS + r * 512 + ((l * 8) ^ ((r & 7) << 4))) = xr[j];
        }
    }

    f32x4 acc[8][4];
#pragma unroll
    for (int nt = 0; nt < 8; ++nt)
#pragma unroll
        for (int rt = 0; rt < 4; ++rt) acc[nt][rt] = (f32x4){0.f, 0.f, 0.f, 0.f};

    const char* W1Tt = (const char*)W1T + (size_t)t * 262144;
    const int ln4 = (l >> 4) * 4;

    __syncthreads();     // X tile visible to all waves

    // ---- barrier-free K-loop: W frags straight from L2, X frags from LDS ----
#pragma unroll
    for (int c = 0; c < 8; ++c) {
        bf16x8 aA[8];
#pragma unroll
        for (int nt = 0; nt < 8; ++nt)
            aA[nt] = *(const bf16x8*)(W1Tt + c * 32768 + (w * 8 + nt) * 1024 + l * 16);
#pragma unroll
        for (int rt = 0; rt < 4; ++rt) {
            const int r = rt * 16 + (l & 15);
            const bf16x8 bX = *(const bf16x8*)(LDS + r * 512 +
                                               ((c * 64 + (l >> 4) * 16) ^ ((r & 7) << 4)));
#pragma unroll
            for (int nt = 0; nt < 8; ++nt)
                acc[nt][rt] = __builtin_amdgcn_mfma_f32_16x16x32_bf16(aA[nt], bX, acc[nt][rt], 0, 0, 0);
        }
    }
    __syncthreads();     // all X reads done; LDS becomes Hr

    // --- epilogue L1: bias+ReLU+BN1, bf16, swizzled row-major Hr[r][n] ---
#pragma unroll
    for (int nt = 0; nt < 8; ++nt) {
        const int n0 = (w * 8 + nt) * 16 + ln4;
        const int o = n0 >> 6, h0 = n0 & 63;
        const int pidx = (o * NT + t) * NH1 + h0;
        const float4 b1v = *(const float4*)(pb1 + pidx);
        const float4 g1v = *(const float4*)(pg1 + pidx);
        const float4 be1v = *(const float4*)(pbe1 + pidx);
        const float4 m1v = *(const float4*)(pm1 + pidx);
        const float4 v1v = *(const float4*)(pv1 + pidx);
        float bb[4], sc[4], sh[4];
        bb[0] = b1v.x; sc[0] = g1v.x * rsqrtf(v1v.x + BNEPS); sh[0] = be1v.x - m1v.x * sc[0];
        bb[1] = b1v.y; sc[1] = g1v.y * rsqrtf(v1v.y + BNEPS); sh[1] = be1v.y - m1v.y * sc[1];
        bb[2] = b1v.z; sc[2] = g1v.z * rsqrtf(v1v.z + BNEPS); sh[2] = be1v.z - m1v.z * sc[2];
        bb[3] = b1v.w; sc[3] = g1v.w * rsqrtf(v1v.w + BNEPS); sh[3] = be1v.w - m1v.w * sc[3];
#pragma unroll
        for (int rt = 0; rt < 4; ++rt) {
            const int r = rt * 16 + (l & 15);
            const f32x4 a = acc[nt][rt];
            const float z0 = fmaf(fmaxf(a[0] + bb[0], 0.f), sc[0], sh[0]);
            const float z1 = fmaf(fmaxf(a[1] + bb[1], 0.f), sc[1], sh[1]);
            const float z2 = fmaf(fmaxf(a[2] + bb[2], 0.f), sc[2], sh[2]);
            const float z3 = fmaf(fmaxf(a[3] + bb[3], 0.f), sc[3], sh[3]);
            uint2 pk;
            pk.x = bfpack2(z0, z1); pk.y = bfpack2(z2, z3);
            *(uint2*)(LDS + r * 1024 + (((unsigned)(n0 * 2)) ^ (unsigned)((r & 7) << 4))) = pk;
        }
    }
    // each wave reads only its own Hr columns -> no barrier needed

    // --- layer 2: C2T[k2][r] = W2T x H, MFMA ---
    bf16x8 aW[2][2][2];   // [oo][kt][ks]
#pragma unroll
    for (int oo = 0; oo < 2; ++oo) {
        const int o = w * 2 + oo;
#pragma unroll
        for (int kt = 0; kt < 2; ++kt)
#pragma unroll
            for (int ks = 0; ks < 2; ++ks)
                aW[oo][kt][ks] = *(const bf16x8*)((const char*)W2T +
                    ((((size_t)t * NO + o) * 2 + kt) * 2 + ks) * 1024 + l * 16);
    }
    f32x4 acc2[2][2][4];
#pragma unroll
    for (int oo = 0; oo < 2; ++oo)
#pragma unroll
        for (int kt = 0; kt < 2; ++kt)
#pragma unroll
            for (int rt2 = 0; rt2 < 4; ++rt2) acc2[oo][kt][rt2] = (f32x4){0.f, 0.f, 0.f, 0.f};

#pragma unroll
    for (int rt2 = 0; rt2 < 4; ++rt2) {
        const int r = rt2 * 16 + (l & 15);
        const unsigned swz = (unsigned)((r & 7) << 4);
#pragma unroll
        for (int ks = 0; ks < 2; ++ks) {
            const int nb = ks * 32 + (l >> 4) * 8;
#pragma unroll
            for (int oo = 0; oo < 2; ++oo) {
                const int n8 = (w * 2 + oo) * 64 + nb;
                const bf16x8 bH = *(const bf16x8*)(LDS + r * 1024 + (((unsigned)(n8 * 2)) ^ swz));
#pragma unroll
                for (int kt = 0; kt < 2; ++kt)
                    acc2[oo][kt][rt2] = __builtin_amdgcn_mfma_f32_16x16x32_bf16(aW[oo][kt][ks], bH, acc2[oo][kt][rt2], 0, 0, 0);
            }
        }
    }

    // --- BN2 + ReLU + layer3 dot, reduce over k2 lane groups ---
    float p[2][4];
#pragma unroll
    for (int oo = 0; oo < 2; ++oo)
#pragma unroll
        for (int rt2 = 0; rt2 < 4; ++rt2) p[oo][rt2] = 0.f;

#pragma unroll
    for (int oo = 0; oo < 2; ++oo) {
        const int o = w * 2 + oo;
#pragma unroll
        for (int kt = 0; kt < 2; ++kt) {
            const int k2 = kt * 16 + ln4;
            const int pidx = (o * NT + t) * NH2 + k2;
            const float4 b2v = *(const float4*)(pb2 + pidx);
            const float4 g2v = *(const float4*)(pg2 + pidx);
            const float4 be2v = *(const float4*)(pbe2 + pidx);
            const float4 m2v = *(const float4*)(pm2 + pidx);
            const float4 v2v = *(const float4*)(pv2 + pidx);
            const float4 w3v = *(const float4*)(W3 + pidx);
            float bb[4], A3[4], C3[4];
            {
                const float s0 = g2v.x * rsqrtf(v2v.x + BNEPS);
                const float s1 = g2v.y * rsqrtf(v2v.y + BNEPS);
                const float s2 = g2v.z * rsqrtf(v2v.z + BNEPS);
                const float s3 = g2v.w * rsqrtf(v2v.w + BNEPS);
                bb[0] = b2v.x; A3[0] = s0 * w3v.x; C3[0] = (be2v.x - m2v.x * s0) * w3v.x;
                bb[1] = b2v.y; A3[1] = s1 * w3v.y; C3[1] = (be2v.y - m2v.y * s1) * w3v.y;
                bb[2] = b2v.z; A3[2] = s2 * w3v.z; C3[2] = (be2v.z - m2v.z * s2) * w3v.z;
                bb[3] = b2v.w; A3[3] = s3 * w3v.w; C3[3] = (be2v.w - m2v.w * s3) * w3v.w;
            }
#pragma unroll
            for (int rt2 = 0; rt2 < 4; ++rt2) {
                const f32x4 a = acc2[oo][kt][rt2];
                float s = fmaf(fmaxf(a[0] + bb[0], 0.f), A3[0], C3[0]);
                s = fmaf(fmaxf(a[1] + bb[1], 0.f), A3[1], s + C3[1]);
                s = fmaf(fmaxf(a[2] + bb[2], 0.f), A3[2], s + C3[2]);
                s = fmaf(fmaxf(a[3] + bb[3], 0.f), A3[3], s + C3[3]);
                p[oo][rt2] += s;
            }
        }
    }
#pragma unroll
    for (int oo = 0; oo < 2; ++oo)
#pragma unroll
        for (int rt2 = 0; rt2 < 4; ++rt2) {
            float v = p[oo][rt2];
            v += __shfl_xor(v, 16);
            v += __shfl_xor(v, 32);
            p[oo][rt2] = v;
        }

    const int oo_s = l >> 5;
    const int bsel = (l >> 4) & 1;
    const int o_s = w * 2 + oo_s;
    const float b3v = pb3[o_s * NT + t];
    const float v0 = oo_s ? (bsel ? p[1][1] : p[1][0]) : (bsel ? p[0][1] : p[0][0]);
    const float v1 = oo_s ? (bsel ? p[1][3] : p[1][2]) : (bsel ? p[0][3] : p[0][2]);
    const int rg0 = bsel * 16 + (l & 15);
    const int ra = __shfl(rid_reg, rg0);
    const int rb = __shfl(rid_reg, rg0 + 32);
    if (ra >= 0) out[(size_t)ra * NO + o_s] = v0 + b3v;
    if (rb >= 0) out[(size_t)rb * NO + o_s] = v1 + b3v;
}

extern "C" void kernel_launch(void* const* d_in, const int* in_sizes, int n_in,
                              void* d_out, int out_size, void* d_ws, size_t ws_size,
                              hipStream_t stream) {
    const float* X   = (const float*)d_in[0];
    const int* trt   = (const int*)d_in[1];
    const float* W1  = (const float*)d_in[2];
    const float* b1  = (const float*)d_in[3];
    const float* g1  = (const float*)d_in[4];
    const float* be1 = (const float*)d_in[5];
    const float* m1  = (const float*)d_in[6];
    const float* v1  = (const float*)d_in[7];
    const float* W2  = (const float*)d_in[8];
    const float* b2  = (const float*)d_in[9];
    const float* g2  = (const float*)d_in[10];
    const float* be2 = (const float*)d_in[11];
    const float* m2  = (const float*)d_in[12];
    const float* v2  = (const float*)d_in[13];
    const float* W3  = (const float*)d_in[14];
    const float* b3  = (const float*)d_in[15];
    float* out = (float*)d_out;

    const int B = in_sizes[1];
    const int permCap = B + NT * BM;                 // padded-bucket capacity
    int* wsi  = (int*)d_ws;
    int* perm = wsi + 16;
    char* wsb = (char*)d_ws;
    size_t off = 64 + (size_t)permCap * 4;
    off = (off + 15) & ~(size_t)15;
    unsigned* W1T4 = (unsigned*)(wsb + off);
    unsigned* W2T4 = (unsigned*)(wsb + off + 1048576);

    const int nb = (B + 255) / 256;
    const int nbi = (permCap + 255) / 256;
    k_init<<<nbi, 256, 0, stream>>>(wsi, perm, permCap);
    k_hist<<<nb, 256, 0, stream>>>(trt, wsi, B);
    k_prefix<<<1, 1, 0, stream>>>(wsi);
    k_scatter<<<nb, 256, 0, stream>>>(trt, wsi, perm, B);
    k_prep<<<288, 256, 0, stream>>>(W1, W2, W1T4, W2T4);

    const int gx = (B + NT * BM) / BM;               // covers padded total
    k_main<<<gx, 256, 0, stream>>>(X, wsi, perm,
                                   (const unsigned short*)W1T4, (const unsigned short*)W2T4,
                                   b1, g1, be1, m1, v1, b2, g2, be2, m2, v2, W3, b3, out);
}

// Round 6
// 61.818 us; speedup vs baseline: 1.1443x; 1.1443x over previous
//
#include <hip/hip_runtime.h>
#include <cstdint>

typedef short bf16x8 __attribute__((ext_vector_type(8)));
typedef float f32x4 __attribute__((ext_vector_type(4)));

#define NO 8
#define NT 4
#define ND 256
#define NH1 64
#define NH2 32
#define BM 32
#define BNEPS 1e-5f

__device__ __forceinline__ unsigned bfpack2(float a, float b) {
    unsigned ua = __float_as_uint(a), ub = __float_as_uint(b);
    ua = (ua + 0x7FFFu + ((ua >> 16) & 1u)) >> 16;
    ub = (ub + 0x7FFFu + ((ub >> 16) & 1u)) >> 16;
    return ua | (ub << 16);
}

// ws layout (bytes, B=65536):
//   [0,64): int cnt[4] @0, cursor[4] @16 (both zeroed by memset)
//   [64, 64+4B): perm (unpadded, contiguous buckets)
//   W1T (1 MB), W2T (128 KB), P1 sc/sh/bb (3x8 KB), P2 A3/C3/bb (3x4 KB)

__global__ void k_hist_prep(const int* __restrict__ trt, int* __restrict__ ws, int B,
                            const float* __restrict__ W1, const float* __restrict__ W2,
                            const float* __restrict__ b1, const float* __restrict__ g1,
                            const float* __restrict__ be1, const float* __restrict__ m1,
                            const float* __restrict__ v1,
                            const float* __restrict__ b2, const float* __restrict__ g2,
                            const float* __restrict__ be2, const float* __restrict__ m2,
                            const float* __restrict__ v2, const float* __restrict__ W3,
                            unsigned* __restrict__ W1T4, unsigned* __restrict__ W2T4,
                            float* __restrict__ P1, float* __restrict__ P2) {
    const int bid = blockIdx.x, tid = threadIdx.x;
    if (bid < 256) {                                      // ---- histogram ----
        __shared__ int loc[NT];
        if (tid < NT) loc[tid] = 0;
        __syncthreads();
        const int i = bid * 256 + tid;
        if (i < B) atomicAdd(&loc[trt[i] & 3], 1);
        __syncthreads();
        if (tid < NT) atomicAdd(&ws[tid], loc[tid]);
    } else if (bid < 512) {                               // ---- W1T frags ----
        const int gi = (bid - 256) * 256 + tid;           // 65536
        const int lane = gi & 63, nt = (gi >> 6) & 31, c = (gi >> 11) & 7, t = gi >> 14;
        const int n16 = lane & 15, kg = lane >> 4;
        const int n = nt * 16 + n16, o = n >> 6, h = n & 63;
        const int k0 = c * 32 + kg * 8;
        const float* src = W1 + ((size_t)(o * NT + t) * ND + k0) * NH1 + h;
        float v[8];
#pragma unroll
        for (int j = 0; j < 8; ++j) v[j] = src[(size_t)j * NH1];
        uint4 q;
        q.x = bfpack2(v[0], v[1]); q.y = bfpack2(v[2], v[3]);
        q.z = bfpack2(v[4], v[5]); q.w = bfpack2(v[6], v[7]);
        ((uint4*)W1T4)[gi] = q;
    } else if (bid < 544) {                               // ---- W2T frags ----
        const int gi = (bid - 512) * 256 + tid;           // 8192
        const int m16 = gi & 15, kg = (gi >> 4) & 3, ks = (gi >> 6) & 1,
                  kt = (gi >> 7) & 1, o = (gi >> 8) & 7, t = gi >> 11;
        const int k2 = kt * 16 + m16, hb = ks * 32 + kg * 8;
        const float* src = W2 + ((size_t)(o * NT + t) * NH1 + hb) * NH2 + k2;
        float v[8];
#pragma unroll
        for (int j = 0; j < 8; ++j) v[j] = src[(size_t)j * NH2];
        uint4 q;
        q.x = bfpack2(v[0], v[1]); q.y = bfpack2(v[2], v[3]);
        q.z = bfpack2(v[4], v[5]); q.w = bfpack2(v[6], v[7]);
        ((uint4*)W2T4)[gi] = q;
    } else if (bid < 552) {                               // ---- P1: BN1 fold ----
        const int gi = (bid - 544) * 256 + tid;           // 2048 = 4t x 512n
        const int t = gi >> 9, n = gi & 511;
        const int o = n >> 6, h = n & 63;
        const int idx = (o * NT + t) * NH1 + h;
        const float sc = g1[idx] * rsqrtf(v1[idx] + BNEPS);
        P1[gi] = sc;                                      // sc
        P1[2048 + gi] = be1[idx] - m1[idx] * sc;          // sh
        P1[4096 + gi] = b1[idx];                          // bb
    } else {                                              // ---- P2: BN2+W3 fold ----
        const int gi = (bid - 552) * 256 + tid;           // 1024 = 4t x 256(o,k2)
        const int t = gi >> 8, q = gi & 255;
        const int o = q >> 5, k2 = q & 31;
        const int idx = (o * NT + t) * NH2 + k2;
        const float s = g2[idx] * rsqrtf(v2[idx] + BNEPS);
        const float w3 = W3[idx];
        P2[gi] = s * w3;                                  // A3
        P2[1024 + gi] = (be2[idx] - m2[idx] * s) * w3;    // C3
        P2[2048 + gi] = b2[idx];                          // bb
    }
}

__global__ void k_scatter(const int* __restrict__ trt, int* __restrict__ ws,
                          int* __restrict__ perm, int B) {
    __shared__ int loc[NT], gb[NT];
    const int tid = threadIdx.x;
    if (tid < NT) loc[tid] = 0;
    __syncthreads();
    const int i = blockIdx.x * blockDim.x + tid;
    int tt = 0, pos = 0;
    if (i < B) { tt = trt[i] & 3; pos = atomicAdd(&loc[tt], 1); }
    __syncthreads();
    if (tid < NT) {
        const int c0 = ws[0], c1 = ws[1], c2 = ws[2];
        const int ub = tid == 0 ? 0 : tid == 1 ? c0 : tid == 2 ? c0 + c1 : c0 + c1 + c2;
        gb[tid] = ub + atomicAdd(&ws[4 + tid], loc[tid]);
    }
    __syncthreads();
    if (i < B) perm[gb[tt] + pos] = i;
}

// ---------------- fused 3-layer expert MLP, 32-row blocks, 12 waves/CU ----------------
__global__ __launch_bounds__(256, 3) void k_main(
    const float* __restrict__ X, const int* __restrict__ ws, const int* __restrict__ perm,
    const char* __restrict__ W1T, const char* __restrict__ W2T,
    const float* __restrict__ P1, const float* __restrict__ P2,
    const float* __restrict__ pb3, float* __restrict__ out)
{
    const int c0 = ws[0], c1 = ws[1], c2 = ws[2], c3 = ws[3];
    const int q0 = (c0 + 31) & ~31, q1 = (c1 + 31) & ~31, q2 = (c2 + 31) & ~31;
    const int e0 = q0, e1 = q0 + q1, e2 = e1 + q2, e3 = e2 + ((c3 + 31) & ~31);
    const int m0 = blockIdx.x * BM;
    if (m0 >= e3) return;
    const int t = (m0 >= e0) + (m0 >= e1) + (m0 >= e2);
    const int pb = t == 0 ? 0 : t == 1 ? e0 : t == 2 ? e1 : e2;
    const int ub = t == 0 ? 0 : t == 1 ? c0 : t == 2 ? c0 + c1 : c0 + c1 + c2;
    const int n_t = t == 0 ? c0 : t == 1 ? c1 : t == 2 ? c2 : c3;
    const int ploc0 = m0 - pb;

    const int tid = threadIdx.x;
    const int w = tid >> 6;
    const int l = tid & 63;

    // [0,16384): X tile [32 r][512 B] bf16 swizzled; after barrier: Hr [32 r][1024 B]
    __shared__ __align__(16) char LDS[32768];

    const int pl = ploc0 + (l & 31);
    const int rid_l = perm[ub + min(pl, n_t - 1)];

    // ---- stage X: each wave loads 8 rows, 1KB coalesced each ----
#pragma unroll
    for (int j = 0; j < 8; ++j) {
        const int r = w * 8 + j;
        const int rr = __shfl(rid_l, r);
        const float4 xv = *(const float4*)(X + (size_t)rr * ND + l * 4);
        uint2 pk;
        pk.x = bfpack2(xv.x, xv.y);
        pk.y = bfpack2(xv.z, xv.w);
        *(uint2*)(LDS + r * 512 + ((l * 8) ^ ((r & 7) << 4))) = pk;
    }

    f32x4 acc[8][2];
#pragma unroll
    for (int nt = 0; nt < 8; ++nt)
#pragma unroll
        for (int rt = 0; rt < 2; ++rt) acc[nt][rt] = (f32x4){0.f, 0.f, 0.f, 0.f};

    const char* W1Tt = W1T + (size_t)t * 262144;
    const int ln4 = (l >> 4) * 4;

    __syncthreads();

    // ---- K-loop: W frags from L2, X frags from LDS; no barriers ----
#pragma unroll
    for (int c = 0; c < 8; ++c) {
        bf16x8 aA[8];
#pragma unroll
        for (int nt = 0; nt < 8; ++nt)
            aA[nt] = *(const bf16x8*)(W1Tt + c * 32768 + (w * 8 + nt) * 1024 + l * 16);
#pragma unroll
        for (int rt = 0; rt < 2; ++rt) {
            const int r = rt * 16 + (l & 15);
            const bf16x8 bX = *(const bf16x8*)(LDS + r * 512 +
                                               ((c * 64 + (l >> 4) * 16) ^ ((r & 7) << 4)));
#pragma unroll
            for (int nt = 0; nt < 8; ++nt)
                acc[nt][rt] = __builtin_amdgcn_mfma_f32_16x16x32_bf16(aA[nt], bX, acc[nt][rt], 0, 0, 0);
        }
    }
    __syncthreads();     // X reads done; LDS becomes Hr

    // ---- epilogue L1: bias+ReLU+BN1 (pre-folded), bf16 swizzled Hr ----
#pragma unroll
    for (int nt = 0; nt < 8; ++nt) {
        const int n0 = (w * 8 + nt) * 16 + ln4;
        const int p = t * 512 + n0;
        const float4 scv = *(const float4*)(P1 + p);
        const float4 shv = *(const float4*)(P1 + 2048 + p);
        const float4 bbv = *(const float4*)(P1 + 4096 + p);
#pragma unroll
        for (int rt = 0; rt < 2; ++rt) {
            const int r = rt * 16 + (l & 15);
            const f32x4 a = acc[nt][rt];
            const float z0 = fmaf(fmaxf(a[0] + bbv.x, 0.f), scv.x, shv.x);
            const float z1 = fmaf(fmaxf(a[1] + bbv.y, 0.f), scv.y, shv.y);
            const float z2 = fmaf(fmaxf(a[2] + bbv.z, 0.f), scv.z, shv.z);
            const float z3 = fmaf(fmaxf(a[3] + bbv.w, 0.f), scv.w, shv.w);
            uint2 pk;
            pk.x = bfpack2(z0, z1); pk.y = bfpack2(z2, z3);
            *(uint2*)(LDS + r * 1024 + (((unsigned)(n0 * 2)) ^ (unsigned)((r & 7) << 4))) = pk;
        }
    }
    // each wave reads only its own Hr columns -> no barrier needed

    // ---- layer 2: MFMA over the wave's 2 outcomes ----
    bf16x8 aW[2][2][2];   // [oo][kt][ks]
#pragma unroll
    for (int oo = 0; oo < 2; ++oo) {
        const int o = w * 2 + oo;
#pragma unroll
        for (int kt = 0; kt < 2; ++kt)
#pragma unroll
            for (int ks = 0; ks < 2; ++ks)
                aW[oo][kt][ks] = *(const bf16x8*)(W2T +
                    ((((size_t)t * NO + o) * 2 + kt) * 2 + ks) * 1024 + l * 16);
    }
    f32x4 acc2[2][2][2];  // [oo][kt][rt2]
#pragma unroll
    for (int oo = 0; oo < 2; ++oo)
#pragma unroll
        for (int kt = 0; kt < 2; ++kt)
#pragma unroll
            for (int rt2 = 0; rt2 < 2; ++rt2) acc2[oo][kt][rt2] = (f32x4){0.f, 0.f, 0.f, 0.f};

#pragma unroll
    for (int rt2 = 0; rt2 < 2; ++rt2) {
        const int r = rt2 * 16 + (l & 15);
        const unsigned swz = (unsigned)((r & 7) << 4);
#pragma unroll
        for (int ks = 0; ks < 2; ++ks) {
            const int nb = ks * 32 + (l >> 4) * 8;
#pragma unroll
            for (int oo = 0; oo < 2; ++oo) {
                const int n8 = (w * 2 + oo) * 64 + nb;
                const bf16x8 bH = *(const bf16x8*)(LDS + r * 1024 + (((unsigned)(n8 * 2)) ^ swz));
#pragma unroll
                for (int kt = 0; kt < 2; ++kt)
                    acc2[oo][kt][rt2] = __builtin_amdgcn_mfma_f32_16x16x32_bf16(aW[oo][kt][ks], bH, acc2[oo][kt][rt2], 0, 0, 0);
            }
        }
    }

    // ---- BN2 + ReLU + layer3 dot (pre-folded), reduce over k-lane-groups ----
    float p[2][2];
#pragma unroll
    for (int oo = 0; oo < 2; ++oo)
#pragma unroll
        for (int rt2 = 0; rt2 < 2; ++rt2) p[oo][rt2] = 0.f;

#pragma unroll
    for (int oo = 0; oo < 2; ++oo) {
        const int o = w * 2 + oo;
#pragma unroll
        for (int kt = 0; kt < 2; ++kt) {
            const int q = o * 32 + kt * 16 + ln4;
            const int p3 = t * 256 + q;
            const float4 A3 = *(const float4*)(P2 + p3);
            const float4 C3 = *(const float4*)(P2 + 1024 + p3);
            const float4 bb = *(const float4*)(P2 + 2048 + p3);
#pragma unroll
            for (int rt2 = 0; rt2 < 2; ++rt2) {
                const f32x4 a = acc2[oo][kt][rt2];
                float s = fmaf(fmaxf(a[0] + bb.x, 0.f), A3.x, C3.x);
                s = fmaf(fmaxf(a[1] + bb.y, 0.f), A3.y, s + C3.y);
                s = fmaf(fmaxf(a[2] + bb.z, 0.f), A3.z, s + C3.z);
                s = fmaf(fmaxf(a[3] + bb.w, 0.f), A3.w, s + C3.w);
                p[oo][rt2] += s;
            }
        }
    }
#pragma unroll
    for (int oo = 0; oo < 2; ++oo)
#pragma unroll
        for (int rt2 = 0; rt2 < 2; ++rt2) {
            float v = p[oo][rt2];
            v += __shfl_xor(v, 16);
            v += __shfl_xor(v, 32);
            p[oo][rt2] = v;
        }

    const int oo_s = l >> 5;
    const int rt2_s = (l >> 4) & 1;
    const int o_s = w * 2 + oo_s;
    const int r = rt2_s * 16 + (l & 15);
    const float v = oo_s ? (rt2_s ? p[1][1] : p[1][0]) : (rt2_s ? p[0][1] : p[0][0]);
    const int ra = __shfl(rid_l, r);
    if (ploc0 + r < n_t) out[(size_t)ra * NO + o_s] = v + pb3[o_s * NT + t];
}

extern "C" void kernel_launch(void* const* d_in, const int* in_sizes, int n_in,
                              void* d_out, int out_size, void* d_ws, size_t ws_size,
                              hipStream_t stream) {
    const float* X   = (const float*)d_in[0];
    const int* trt   = (const int*)d_in[1];
    const float* W1  = (const float*)d_in[2];
    const float* b1  = (const float*)d_in[3];
    const float* g1  = (const float*)d_in[4];
    const float* be1 = (const float*)d_in[5];
    const float* m1  = (const float*)d_in[6];
    const float* v1  = (const float*)d_in[7];
    const float* W2  = (const float*)d_in[8];
    const float* b2  = (const float*)d_in[9];
    const float* g2  = (const float*)d_in[10];
    const float* be2 = (const float*)d_in[11];
    const float* m2  = (const float*)d_in[12];
    const float* v2  = (const float*)d_in[13];
    const float* W3  = (const float*)d_in[14];
    const float* b3  = (const float*)d_in[15];
    float* out = (float*)d_out;

    const int B = in_sizes[1];
    int* wsi  = (int*)d_ws;
    int* perm = wsi + 16;
    char* wsb = (char*)d_ws;
    size_t off = (64 + (size_t)B * 4 + 15) & ~(size_t)15;
    char* W1T = wsb + off;
    char* W2T = W1T + 1048576;
    float* P1 = (float*)(W2T + 131072);
    float* P2 = P1 + 6144;

    hipMemsetAsync(wsi, 0, 64, stream);
    k_hist_prep<<<556, 256, 0, stream>>>(trt, wsi, B, W1, W2,
                                         b1, g1, be1, m1, v1,
                                         b2, g2, be2, m2, v2, W3,
                                         (unsigned*)W1T, (unsigned*)W2T, P1, P2);
    k_scatter<<<(B + 255) / 256, 256, 0, stream>>>(trt, wsi, perm, B);

    const int gx = (B + 31) / 32 + 4;                // covers worst-case bucket padding
    k_main<<<gx, 256, 0, stream>>>(X, wsi, perm, W1T, W2T, P1, P2, b3, out);
}

// Round 7
// 59.470 us; speedup vs baseline: 1.1895x; 1.0395x over previous
//
#include <hip/hip_runtime.h>
#include <cstdint>

typedef short bf16x8 __attribute__((ext_vector_type(8)));
typedef float f32x4 __attribute__((ext_vector_type(4)));

#define NO 8
#define NT 4
#define ND 256
#define NH1 64
#define NH2 32
#define BM 32
#define BNEPS 1e-5f

__device__ __forceinline__ unsigned bfpack2(float a, float b) {
    unsigned ua = __float_as_uint(a), ub = __float_as_uint(b);
    ua = (ua + 0x7FFFu + ((ua >> 16) & 1u)) >> 16;
    ub = (ub + 0x7FFFu + ((ub >> 16) & 1u)) >> 16;
    return ua | (ub << 16);
}

// ws layout (bytes, B=65536):
//   [0,64): int cnt[4] @0, cursor[4] @16 (both zeroed by memset)
//   [64, 64+4B): perm (unpadded, contiguous buckets)
//   W1T (1 MB), W2T (128 KB), P1 sc/sh/bb (3x8 KB), P2 A3/C3/bb (3x4 KB)

__global__ void k_hist_prep(const int* __restrict__ trt, int* __restrict__ ws, int B,
                            const float* __restrict__ W1, const float* __restrict__ W2,
                            const float* __restrict__ b1, const float* __restrict__ g1,
                            const float* __restrict__ be1, const float* __restrict__ m1,
                            const float* __restrict__ v1,
                            const float* __restrict__ b2, const float* __restrict__ g2,
                            const float* __restrict__ be2, const float* __restrict__ m2,
                            const float* __restrict__ v2, const float* __restrict__ W3,
                            unsigned* __restrict__ W1T4, unsigned* __restrict__ W2T4,
                            float* __restrict__ P1, float* __restrict__ P2) {
    const int bid = blockIdx.x, tid = threadIdx.x;
    if (bid < 256) {                                      // ---- histogram ----
        __shared__ int loc[NT];
        if (tid < NT) loc[tid] = 0;
        __syncthreads();
        const int i = bid * 256 + tid;
        if (i < B) atomicAdd(&loc[trt[i] & 3], 1);
        __syncthreads();
        if (tid < NT) atomicAdd(&ws[tid], loc[tid]);
    } else if (bid < 512) {                               // ---- W1T frags ----
        const int gi = (bid - 256) * 256 + tid;           // 65536
        const int lane = gi & 63, nt = (gi >> 6) & 31, c = (gi >> 11) & 7, t = gi >> 14;
        const int n16 = lane & 15, kg = lane >> 4;
        const int n = nt * 16 + n16, o = n >> 6, h = n & 63;
        const int k0 = c * 32 + kg * 8;
        const float* src = W1 + ((size_t)(o * NT + t) * ND + k0) * NH1 + h;
        float v[8];
#pragma unroll
        for (int j = 0; j < 8; ++j) v[j] = src[(size_t)j * NH1];
        uint4 q;
        q.x = bfpack2(v[0], v[1]); q.y = bfpack2(v[2], v[3]);
        q.z = bfpack2(v[4], v[5]); q.w = bfpack2(v[6], v[7]);
        ((uint4*)W1T4)[gi] = q;
    } else if (bid < 544) {                               // ---- W2T frags ----
        const int gi = (bid - 512) * 256 + tid;           // 8192
        const int m16 = gi & 15, kg = (gi >> 4) & 3, ks = (gi >> 6) & 1,
                  kt = (gi >> 7) & 1, o = (gi >> 8) & 7, t = gi >> 11;
        const int k2 = kt * 16 + m16, hb = ks * 32 + kg * 8;
        const float* src = W2 + ((size_t)(o * NT + t) * NH1 + hb) * NH2 + k2;
        float v[8];
#pragma unroll
        for (int j = 0; j < 8; ++j) v[j] = src[(size_t)j * NH2];
        uint4 q;
        q.x = bfpack2(v[0], v[1]); q.y = bfpack2(v[2], v[3]);
        q.z = bfpack2(v[4], v[5]); q.w = bfpack2(v[6], v[7]);
        ((uint4*)W2T4)[gi] = q;
    } else if (bid < 552) {                               // ---- P1: BN1 fold ----
        const int gi = (bid - 544) * 256 + tid;           // 2048 = 4t x 512n
        const int t = gi >> 9, n = gi & 511;
        const int o = n >> 6, h = n & 63;
        const int idx = (o * NT + t) * NH1 + h;
        const float sc = g1[idx] * rsqrtf(v1[idx] + BNEPS);
        P1[gi] = sc;                                      // sc
        P1[2048 + gi] = be1[idx] - m1[idx] * sc;          // sh
        P1[4096 + gi] = b1[idx];                          // bb
    } else {                                              // ---- P2: BN2+W3 fold ----
        const int gi = (bid - 552) * 256 + tid;           // 1024 = 4t x 256(o,k2)
        const int t = gi >> 8, q = gi & 255;
        const int o = q >> 5, k2 = q & 31;
        const int idx = (o * NT + t) * NH2 + k2;
        const float s = g2[idx] * rsqrtf(v2[idx] + BNEPS);
        const float w3 = W3[idx];
        P2[gi] = s * w3;                                  // A3
        P2[1024 + gi] = (be2[idx] - m2[idx] * s) * w3;    // C3
        P2[2048 + gi] = b2[idx];                          // bb
    }
}

__global__ void k_scatter(const int* __restrict__ trt, int* __restrict__ ws,
                          int* __restrict__ perm, int B) {
    __shared__ int loc[NT], gb[NT];
    const int tid = threadIdx.x;
    if (tid < NT) loc[tid] = 0;
    __syncthreads();
    const int i = blockIdx.x * blockDim.x + tid;
    int tt = 0, pos = 0;
    if (i < B) { tt = trt[i] & 3; pos = atomicAdd(&loc[tt], 1); }
    __syncthreads();
    if (tid < NT) {
        const int c0 = ws[0], c1 = ws[1], c2 = ws[2];
        const int ub = tid == 0 ? 0 : tid == 1 ? c0 : tid == 2 ? c0 + c1 : c0 + c1 + c2;
        gb[tid] = ub + atomicAdd(&ws[4 + tid], loc[tid]);
    }
    __syncthreads();
    if (i < B) perm[gb[tt] + pos] = i;
}

// ---------------- fused 3-layer expert MLP, 32-row blocks, reg-dbuf W prefetch ----------------
__global__ __launch_bounds__(256, 3) void k_main(
    const float* __restrict__ X, const int* __restrict__ ws, const int* __restrict__ perm,
    const char* __restrict__ W1T, const char* __restrict__ W2T,
    const float* __restrict__ P1, const float* __restrict__ P2,
    const float* __restrict__ pb3, float* __restrict__ out)
{
    const int c0 = ws[0], c1 = ws[1], c2 = ws[2], c3 = ws[3];
    const int q0 = (c0 + 31) & ~31, q1 = (c1 + 31) & ~31, q2 = (c2 + 31) & ~31;
    const int e0 = q0, e1 = q0 + q1, e2 = e1 + q2, e3 = e2 + ((c3 + 31) & ~31);
    const int m0 = blockIdx.x * BM;
    if (m0 >= e3) return;
    const int t = (m0 >= e0) + (m0 >= e1) + (m0 >= e2);
    const int pb = t == 0 ? 0 : t == 1 ? e0 : t == 2 ? e1 : e2;
    const int ub = t == 0 ? 0 : t == 1 ? c0 : t == 2 ? c0 + c1 : c0 + c1 + c2;
    const int n_t = t == 0 ? c0 : t == 1 ? c1 : t == 2 ? c2 : c3;
    const int ploc0 = m0 - pb;

    const int tid = threadIdx.x;
    const int w = tid >> 6;
    const int l = tid & 63;

    // [0,16384): X tile [32 r][512 B] bf16 swizzled; after barrier: Hr [32 r][1024 B]
    __shared__ __align__(16) char LDS[32768];

    const int pl = ploc0 + (l & 31);
    const int rid_l = perm[ub + min(pl, n_t - 1)];

    // ---- stage X: each wave loads 8 rows, 1KB coalesced each ----
#pragma unroll
    for (int j = 0; j < 8; ++j) {
        const int r = w * 8 + j;
        const int rr = __shfl(rid_l, r);
        const float4 xv = *(const float4*)(X + (size_t)rr * ND + l * 4);
        uint2 pk;
        pk.x = bfpack2(xv.x, xv.y);
        pk.y = bfpack2(xv.z, xv.w);
        *(uint2*)(LDS + r * 512 + ((l * 8) ^ ((r & 7) << 4))) = pk;
    }

    f32x4 acc[8][2];
#pragma unroll
    for (int nt = 0; nt < 8; ++nt)
#pragma unroll
        for (int rt = 0; rt < 2; ++rt) acc[nt][rt] = (f32x4){0.f, 0.f, 0.f, 0.f};

    const char* W1Tt = W1T + (size_t)t * 262144;
    const char* W1Tw = W1Tt + (w * 8) * 1024 + l * 16;
    const int ln4 = (l >> 4) * 4;

    // prologue of reg-dbuf: issue chunk-0 W frags before the barrier
    bf16x8 aA[8], aB[8];
#pragma unroll
    for (int nt = 0; nt < 8; ++nt)
        aA[nt] = *(const bf16x8*)(W1Tw + nt * 1024);

    __syncthreads();

    // ---- K-loop: chunk c+1 W frags issued BEFORE chunk c MFMAs (explicit reg dbuf) ----
#pragma unroll
    for (int c = 0; c < 8; ++c) {
        if (c < 7) {
            if ((c & 1) == 0) {
#pragma unroll
                for (int nt = 0; nt < 8; ++nt)
                    aB[nt] = *(const bf16x8*)(W1Tw + (c + 1) * 32768 + nt * 1024);
            } else {
#pragma unroll
                for (int nt = 0; nt < 8; ++nt)
                    aA[nt] = *(const bf16x8*)(W1Tw + (c + 1) * 32768 + nt * 1024);
            }
        }
#pragma unroll
        for (int rt = 0; rt < 2; ++rt) {
            const int r = rt * 16 + (l & 15);
            const bf16x8 bX = *(const bf16x8*)(LDS + r * 512 +
                                               ((c * 64 + (l >> 4) * 16) ^ ((r & 7) << 4)));
            if ((c & 1) == 0) {
#pragma unroll
                for (int nt = 0; nt < 8; ++nt)
                    acc[nt][rt] = __builtin_amdgcn_mfma_f32_16x16x32_bf16(aA[nt], bX, acc[nt][rt], 0, 0, 0);
            } else {
#pragma unroll
                for (int nt = 0; nt < 8; ++nt)
                    acc[nt][rt] = __builtin_amdgcn_mfma_f32_16x16x32_bf16(aB[nt], bX, acc[nt][rt], 0, 0, 0);
            }
        }
    }
    __syncthreads();     // X reads done; LDS becomes Hr

    // ---- epilogue L1: bias+ReLU+BN1 (pre-folded), bf16 swizzled Hr ----
#pragma unroll
    for (int nt = 0; nt < 8; ++nt) {
        const int n0 = (w * 8 + nt) * 16 + ln4;
        const int p = t * 512 + n0;
        const float4 scv = *(const float4*)(P1 + p);
        const float4 shv = *(const float4*)(P1 + 2048 + p);
        const float4 bbv = *(const float4*)(P1 + 4096 + p);
#pragma unroll
        for (int rt = 0; rt < 2; ++rt) {
            const int r = rt * 16 + (l & 15);
            const f32x4 a = acc[nt][rt];
            const float z0 = fmaf(fmaxf(a[0] + bbv.x, 0.f), scv.x, shv.x);
            const float z1 = fmaf(fmaxf(a[1] + bbv.y, 0.f), scv.y, shv.y);
            const float z2 = fmaf(fmaxf(a[2] + bbv.z, 0.f), scv.z, shv.z);
            const float z3 = fmaf(fmaxf(a[3] + bbv.w, 0.f), scv.w, shv.w);
            uint2 pk;
            pk.x = bfpack2(z0, z1); pk.y = bfpack2(z2, z3);
            *(uint2*)(LDS + r * 1024 + (((unsigned)(n0 * 2)) ^ (unsigned)((r & 7) << 4))) = pk;
        }
    }
    // each wave reads only its own Hr columns -> no barrier needed

    // ---- layer 2: MFMA over the wave's 2 outcomes ----
    bf16x8 aW[2][2][2];   // [oo][kt][ks]
#pragma unroll
    for (int oo = 0; oo < 2; ++oo) {
        const int o = w * 2 + oo;
#pragma unroll
        for (int kt = 0; kt < 2; ++kt)
#pragma unroll
            for (int ks = 0; ks < 2; ++ks)
                aW[oo][kt][ks] = *(const bf16x8*)(W2T +
                    ((((size_t)t * NO + o) * 2 + kt) * 2 + ks) * 1024 + l * 16);
    }
    f32x4 acc2[2][2][2];  // [oo][kt][rt2]
#pragma unroll
    for (int oo = 0; oo < 2; ++oo)
#pragma unroll
        for (int kt = 0; kt < 2; ++kt)
#pragma unroll
            for (int rt2 = 0; rt2 < 2; ++rt2) acc2[oo][kt][rt2] = (f32x4){0.f, 0.f, 0.f, 0.f};

#pragma unroll
    for (int rt2 = 0; rt2 < 2; ++rt2) {
        const int r = rt2 * 16 + (l & 15);
        const unsigned swz = (unsigned)((r & 7) << 4);
#pragma unroll
        for (int ks = 0; ks < 2; ++ks) {
            const int nb = ks * 32 + (l >> 4) * 8;
#pragma unroll
            for (int oo = 0; oo < 2; ++oo) {
                const int n8 = (w * 2 + oo) * 64 + nb;
                const bf16x8 bH = *(const bf16x8*)(LDS + r * 1024 + (((unsigned)(n8 * 2)) ^ swz));
#pragma unroll
                for (int kt = 0; kt < 2; ++kt)
                    acc2[oo][kt][rt2] = __builtin_amdgcn_mfma_f32_16x16x32_bf16(aW[oo][kt][ks], bH, acc2[oo][kt][rt2], 0, 0, 0);
            }
        }
    }

    // ---- BN2 + ReLU + layer3 dot (pre-folded), reduce over k-lane-groups ----
    float p[2][2];
#pragma unroll
    for (int oo = 0; oo < 2; ++oo)
#pragma unroll
        for (int rt2 = 0; rt2 < 2; ++rt2) p[oo][rt2] = 0.f;

#pragma unroll
    for (int oo = 0; oo < 2; ++oo) {
        const int o = w * 2 + oo;
#pragma unroll
        for (int kt = 0; kt < 2; ++kt) {
            const int q = o * 32 + kt * 16 + ln4;
            const int p3 = t * 256 + q;
            const float4 A3 = *(const float4*)(P2 + p3);
            const float4 C3 = *(const float4*)(P2 + 1024 + p3);
            const float4 bb = *(const float4*)(P2 + 2048 + p3);
#pragma unroll
            for (int rt2 = 0; rt2 < 2; ++rt2) {
                const f32x4 a = acc2[oo][kt][rt2];
                float s = fmaf(fmaxf(a[0] + bb.x, 0.f), A3.x, C3.x);
                s = fmaf(fmaxf(a[1] + bb.y, 0.f), A3.y, s + C3.y);
                s = fmaf(fmaxf(a[2] + bb.z, 0.f), A3.z, s + C3.z);
                s = fmaf(fmaxf(a[3] + bb.w, 0.f), A3.w, s + C3.w);
                p[oo][rt2] += s;
            }
        }
    }
#pragma unroll
    for (int oo = 0; oo < 2; ++oo)
#pragma unroll
        for (int rt2 = 0; rt2 < 2; ++rt2) {
            float v = p[oo][rt2];
            v += __shfl_xor(v, 16);
            v += __shfl_xor(v, 32);
            p[oo][rt2] = v;
        }

    const int oo_s = l >> 5;
    const int rt2_s = (l >> 4) & 1;
    const int o_s = w * 2 + oo_s;
    const int r = rt2_s * 16 + (l & 15);
    const float v = oo_s ? (rt2_s ? p[1][1] : p[1][0]) : (rt2_s ? p[0][1] : p[0][0]);
    const int ra = __shfl(rid_l, r);
    if (ploc0 + r < n_t) out[(size_t)ra * NO + o_s] = v + pb3[o_s * NT + t];
}

extern "C" void kernel_launch(void* const* d_in, const int* in_sizes, int n_in,
                              void* d_out, int out_size, void* d_ws, size_t ws_size,
                              hipStream_t stream) {
    const float* X   = (const float*)d_in[0];
    const int* trt   = (const int*)d_in[1];
    const float* W1  = (const float*)d_in[2];
    const float* b1  = (const float*)d_in[3];
    const float* g1  = (const float*)d_in[4];
    const float* be1 = (const float*)d_in[5];
    const float* m1  = (const float*)d_in[6];
    const float* v1  = (const float*)d_in[7];
    const float* W2  = (const float*)d_in[8];
    const float* b2  = (const float*)d_in[9];
    const float* g2  = (const float*)d_in[10];
    const float* be2 = (const float*)d_in[11];
    const float* m2  = (const float*)d_in[12];
    const float* v2  = (const float*)d_in[13];
    const float* W3  = (const float*)d_in[14];
    const float* b3  = (const float*)d_in[15];
    float* out = (float*)d_out;

    const int B = in_sizes[1];
    int* wsi  = (int*)d_ws;
    int* perm = wsi + 16;
    char* wsb = (char*)d_ws;
    size_t off = (64 + (size_t)B * 4 + 15) & ~(size_t)15;
    char* W1T = wsb + off;
    char* W2T = W1T + 1048576;
    float* P1 = (float*)(W2T + 131072);
    float* P2 = P1 + 6144;

    hipMemsetAsync(wsi, 0, 64, stream);
    k_hist_prep<<<556, 256, 0, stream>>>(trt, wsi, B, W1, W2,
                                         b1, g1, be1, m1, v1,
                                         b2, g2, be2, m2, v2, W3,
                                         (unsigned*)W1T, (unsigned*)W2T, P1, P2);
    k_scatter<<<(B + 255) / 256, 256, 0, stream>>>(trt, wsi, perm, B);

    const int gx = (B + 31) / 32 + 4;                // covers worst-case bucket padding
    k_main<<<gx, 256, 0, stream>>>(X, wsi, perm, W1T, W2T, P1, P2, b3, out);
}